// Round 1
// baseline (114.579 us; speedup 1.0000x reference)
//
#include <hip/hip_runtime.h>
#include <hip/hip_fp16.h>

#define ACN_EPS   0.001f
#define ACN_LOG2E 1.4426950408889634f
#define ACN_LN2   0.6931471805599453f
#define TBL_N     2048
#define TBL_LO    -8.0f
#define TBL_SCALE 128.0f      // TBL_N / (HI-LO) = 2048/16
#define TBL_OFF   1024.0f     // -TBL_LO * TBL_SCALE
#define TBL_MAX_T 2047.999f

typedef float v4f  __attribute__((ext_vector_type(4)));
typedef unsigned int u32;
typedef u32 v4u __attribute__((ext_vector_type(4)));

// ---------------------------------------------------------------------------
// Per-element interpolation: fma/med3/cvt -> one ds_read_b32 gather ->
// 2x cvt_f32_f16 -> interp fma. Memory-bound.
// ---------------------------------------------------------------------------
__device__ __forceinline__ float acn_interp(const u32* tbl, float xx) {
    float t  = fmaf(xx, TBL_SCALE, TBL_OFF);
    t        = __builtin_amdgcn_fmed3f(t, 0.0f, TBL_MAX_T);
    int   ii = (int)t;
    float f  = t - (float)ii;
    u32 u = tbl[ii];
    __half2 hv = *(const __half2*)&u;
    return fmaf(__high2float(hv), f, __low2float(hv));
}

__device__ __forceinline__ v4f acn_interp4(const u32* tbl, v4f xv) {
    v4f r;
    r.x = acn_interp(tbl, xv.x);
    r.y = acn_interp(tbl, xv.y);
    r.z = acn_interp(tbl, xv.z);
    r.w = acn_interp(tbl, xv.w);
    return r;
}

// ---------------------------------------------------------------------------
// Fused kernel: each block builds the 2048-interval piecewise-linear table of
// F over [-8,8] directly in its own LDS (256 threads x 8 intervals, 9 shared
// evals/thread; k-outer / point-inner keeps live registers ~55), then streams
// 16 v4f elements/thread. First x-loads are issued BEFORE the build so HBM
// traffic flies underneath the ~3 us VALU burst. Removes the separate
// acn_build launch, the workspace round-trip, and the per-block T staging.
// ---------------------------------------------------------------------------
__global__ __launch_bounds__(256, 4) void acn_fused(
        const v4f* __restrict__ x,
        v4f* __restrict__ out,
        const float* __restrict__ mean,
        const float* __restrict__ variance,
        const float* __restrict__ prior,
        int n4) {
    __shared__ u32 tbl[TBL_N];

    const int Tn  = gridDim.x * blockDim.x;   // 1024*256 = 262144
    const int idx = blockIdx.x * blockDim.x + threadIdx.x;
    const bool fast = (n4 == 16 * Tn);

    // Prefetch the first element pair so the loads are in flight during build.
    v4f a, b;
    if (fast) { a = x[idx]; b = x[idx + Tn]; }

    // ---- table build (all-intrinsic math; uniform params -> s_loads) ----
    {
        float e[8];
        float mx = -1e30f;
#pragma unroll
        for (int k = 0; k < 8; ++k) { e[k] = prior[k]; mx = fmaxf(mx, e[k]); }
        float sum = 0.0f;
#pragma unroll
        for (int k = 0; k < 8; ++k) {
            e[k] = __builtin_amdgcn_exp2f((e[k] - mx) * ACN_LOG2E);
            sum += e[k];
        }
        float rs = __builtin_amdgcn_rcpf(sum);

        const float h  = 1.0f / TBL_SCALE;
        const float x0 = TBL_LO + (float)(threadIdx.x * 8) * h;

        float denom[9], S[9];
#pragma unroll
        for (int j = 0; j < 9; ++j) { denom[j] = 0.0f; S[j] = 0.0f; }

#pragma unroll
        for (int k = 0; k < 8; ++k) {
            float pk = e[k] * rs;                                 // softmax(prior)
            // softplus(v) = ln(1 + e^v) = log2(1 + 2^(v*log2e)) * ln2
            float v  = __builtin_amdgcn_logf(1.0f +
                         __builtin_amdgcn_exp2f(variance[k] * ACN_LOG2E)) * ACN_LN2;
            float ve = v + ACN_EPS;
            float rv  = __builtin_amdgcn_rcpf(v);
            float rve = __builtin_amdgcn_rcpf(ve);
            float mu  = mean[k];
            float s1  = -0.5f * ACN_LOG2E * rv * rv;
            float s2  = -0.5f * ACN_LOG2E * rve * rve;
            float lp  = __builtin_amdgcn_logf(pk);
            float lw  = lp - 0.5f * __builtin_amdgcn_logf(pk + ACN_EPS)
                           - 0.5f * __builtin_amdgcn_logf(ve);
#pragma unroll
            for (int j = 0; j < 9; ++j) {
                float d  = x0 + (float)j * h - mu;
                float d2 = d * d;
                denom[j] += __builtin_amdgcn_exp2f(fmaf(s1, d2, lp));
                S[j] = fmaf(__builtin_amdgcn_exp2f(fmaf(s2, d2, lw)), d, S[j]);
            }
        }

        u32 packed[8];
        float y_prev = S[0] * __builtin_amdgcn_rcpf(denom[0] + ACN_EPS);
#pragma unroll
        for (int j = 0; j < 8; ++j) {
            float y_next = S[j + 1] * __builtin_amdgcn_rcpf(denom[j + 1] + ACN_EPS);
            __half2 hv = __halves2half2(__float2half(y_prev),
                                        __float2half(y_next - y_prev));
            packed[j] = *(const u32*)&hv;
            y_prev = y_next;
        }
        // 8 consecutive dwords per thread -> two b128 writes (one-time cost).
        *(v4u*)&tbl[threadIdx.x * 8]     = *(v4u*)&packed[0];
        *(v4u*)&tbl[threadIdx.x * 8 + 4] = *(v4u*)&packed[4];
    }
    __syncthreads();

    // ---- streaming main loop ----
    if (fast) {
#pragma unroll
        for (int c = 0; c < 8; ++c) {
            const int i = idx + c * 2 * Tn;
            v4f an, bn;
            if (c < 7) {                // prefetch next pair before compute
                an = x[i + 2 * Tn];
                bn = x[i + 3 * Tn];
            }
            __builtin_nontemporal_store(acn_interp4(tbl, a), &out[i]);
            __builtin_nontemporal_store(acn_interp4(tbl, b), &out[i + Tn]);
            if (c < 7) { a = an; b = bn; }
        }
    } else {                            // generic fallback
        for (int i = idx; i < n4; i += Tn) {
            __builtin_nontemporal_store(acn_interp4(tbl, x[i]), &out[i]);
        }
    }
}

extern "C" void kernel_launch(void* const* d_in, const int* in_sizes, int n_in,
                              void* d_out, int out_size, void* d_ws, size_t ws_size,
                              hipStream_t stream) {
    const float* x        = (const float*)d_in[0];
    const float* mean     = (const float*)d_in[1];
    const float* variance = (const float*)d_in[2];
    const float* prior    = (const float*)d_in[3];
    float* out = (float*)d_out;
    (void)d_ws; (void)ws_size;

    int n4 = out_size / 4;        // 4,194,304 = 16 * (1024*256)
    const int block = 256;
    const int grid  = 1024;       // all blocks resident: 4/CU, 16 waves/CU
    acn_fused<<<grid, block, 0, stream>>>((const v4f*)x, (v4f*)out,
                                          mean, variance, prior, n4);
}